// Round 4
// baseline (8334.505 us; speedup 1.0000x reference)
//
#include <hip/hip_runtime.h>

#define BB 64
#define TT 4995
#define VV 4096
#define EE 100
#define UU 64
#define U3 192

// embW[v][k] = (emb @ W1 + b1[0])[v][k], 3.07 MB, L2-resident.
__device__ float g_embW[VV * U3];

__device__ __forceinline__ float fast_sigmoid(float x) {
    return __builtin_amdgcn_rcpf(1.0f + __expf(-x));
}
__device__ __forceinline__ float fast_tanh(float x) {
    return __builtin_amdgcn_rcpf(1.0f + __expf(-2.0f * x)) * 2.0f - 1.0f;
}
// Broadcast lane `lane` of v to all lanes (v_readlane -> SGPR, feeds FMA).
__device__ __forceinline__ float lane_bcast(float v, int lane) {
    return __int_as_float(__builtin_amdgcn_readlane(__float_as_int(v), lane));
}

__global__ void gru_embw_kernel(const float* __restrict__ emb,
                                const float* __restrict__ W1,
                                const float* __restrict__ b1) {
    __shared__ float row[EE];
    const int v = blockIdx.x;
    const int k = threadIdx.x;  // 0..191
    if (k < EE) row[k] = emb[v * EE + k];
    __syncthreads();
    float acc = b1[k];
    #pragma unroll 4
    for (int j = 0; j < EE; ++j)
        acc = fmaf(row[j], W1[j * U3 + k], acc);
    g_embW[v * U3 + k] = acc;
}

// Fused 2-layer GRU scan. One workgroup (192 thr = 3 waves) per batch element.
// wave 0 -> z gate, wave 1 -> r gate, wave 2 -> candidate pieces.
// h1/h2 replicated per wave in registers; dots broadcast h via v_readlane
// on each wave's own SIMD. Weights PINNED in VGPRs via asm value barrier —
// without it LLVM sinks the (rematerializable) global loads into the loop
// and we pay ~147 KB/step of L2 traffic (rounds 2-3 bottleneck, VGPR=108).
__global__ __launch_bounds__(192, 1)
void gru_scan_kernel(const int* __restrict__ tokens,
                     const float* __restrict__ U1,
                     const float* __restrict__ b1,
                     const float* __restrict__ W2,
                     const float* __restrict__ U2,
                     const float* __restrict__ b2,
                     const float* __restrict__ Wout,
                     const float* __restrict__ bout,
                     float* __restrict__ out) {
    const int b = blockIdx.x;
    const int k = threadIdx.x;       // global col 0..191
    const int lane = k & 63;
    const int wave = k >> 6;         // 0=z, 1=r, 2=hh

    __shared__ float g1z[UU], g1r[UU], g1xh[UU], g1hph[UU];
    __shared__ float g2z[UU], g2r[UU], g2xh[UU], g2hph[UU];

    // Weight columns — loaded once, pinned into VGPRs (192 regs).
    float u1c[UU], w2c[UU], u2c[UU];
    #pragma unroll
    for (int j = 0; j < UU; ++j) {
        u1c[j] = U1[j * U3 + k];
        w2c[j] = W2[j * U3 + k];
        u2c[j] = U2[j * U3 + k];
    }
    #pragma unroll
    for (int j = 0; j < UU; ++j) {
        asm volatile("" : "+v"(u1c[j]), "+v"(w2c[j]), "+v"(u2c[j]));
    }
    const float bu1 = b1[U3 + k];   // recurrent bias, layer 1
    const float b20 = b2[k];        // input bias, layer 2
    const float b21 = b2[U3 + k];   // recurrent bias, layer 2

    float hv1 = 0.0f, hv2 = 0.0f;   // h1[lane], h2[lane], replicated per wave

    const int* tokb = tokens + b * TT;
    int tok1 = tokb[1];
    float xk = g_embW[tokb[0] * U3 + k];   // xp1 (input bias folded in)

    #pragma unroll 1
    for (int t = 0; t < TT; ++t) {
        // prefetch: token 2 ahead, embW row 1 ahead (hides L2 latency)
        const int tnn = (t + 2 < TT) ? (t + 2) : (TT - 1);
        const int tok_nn = tokb[tnn];
        const float xk_next = g_embW[tok1 * U3 + k];

        // ---- layer-1 dot: acc = bu1 + sum_j h1[j] * U1[j, k] ----
        float a0 = bu1, a1 = 0.0f;
        #pragma unroll
        for (int j = 0; j < UU; j += 2) {
            a0 = fmaf(lane_bcast(hv1, j),     u1c[j],     a0);
            a1 = fmaf(lane_bcast(hv1, j + 1), u1c[j + 1], a1);
        }
        const float acc = a0 + a1;

        if (wave == 0)      g1z[lane] = fast_sigmoid(xk + acc);
        else if (wave == 1) g1r[lane] = fast_sigmoid(xk + acc);
        else              { g1xh[lane] = xk; g1hph[lane] = acc; }
        __syncthreads();                                   // barrier 1

        // ---- h1 update: all waves redundantly, in-register ----
        {
            const float z  = g1z[lane];
            const float r  = g1r[lane];
            const float hh = fast_tanh(g1xh[lane] + r * g1hph[lane]);
            hv1 = z * hv1 + (1.0f - z) * hh;
        }

        // ---- layer-2 dual dot: c1 = b20 + h1.W2[:,k], c2 = b21 + h2.U2[:,k]
        float c1 = b20, c2 = b21;
        #pragma unroll
        for (int j = 0; j < UU; ++j) {
            c1 = fmaf(lane_bcast(hv1, j), w2c[j], c1);
            c2 = fmaf(lane_bcast(hv2, j), u2c[j], c2);
        }

        if (wave == 0)      g2z[lane] = fast_sigmoid(c1 + c2);
        else if (wave == 1) g2r[lane] = fast_sigmoid(c1 + c2);
        else              { g2xh[lane] = c1; g2hph[lane] = c2; }
        __syncthreads();                                   // barrier 2

        // ---- h2 update: all waves redundantly, in-register ----
        {
            const float z  = g2z[lane];
            const float r  = g2r[lane];
            const float hh = fast_tanh(g2xh[lane] + r * g2hph[lane]);
            hv2 = z * hv2 + (1.0f - z) * hh;
        }

        xk = xk_next;
        tok1 = tok_nn;
    }

    // ---- output head: out[b] = sigmoid(h2 . Wout + bout) ----
    if (wave == 0) {
        float s = bout[0];
        #pragma unroll
        for (int j = 0; j < UU; ++j)
            s = fmaf(lane_bcast(hv2, j), Wout[j], s);
        if (lane == 0) out[b] = fast_sigmoid(s);
    }
}

extern "C" void kernel_launch(void* const* d_in, const int* in_sizes, int n_in,
                              void* d_out, int out_size, void* d_ws, size_t ws_size,
                              hipStream_t stream) {
    const int*   tokens = (const int*)  d_in[0];
    const float* emb    = (const float*)d_in[1];
    const float* W1     = (const float*)d_in[2];
    const float* U1w    = (const float*)d_in[3];
    const float* b1     = (const float*)d_in[4];
    const float* W2     = (const float*)d_in[5];
    const float* U2w    = (const float*)d_in[6];
    const float* b2     = (const float*)d_in[7];
    const float* Wout   = (const float*)d_in[8];
    const float* bout   = (const float*)d_in[9];
    float* out = (float*)d_out;

    gru_embw_kernel<<<VV, 192, 0, stream>>>(emb, W1, b1);
    gru_scan_kernel<<<BB, 192, 0, stream>>>(tokens, U1w, b1, W2, U2w,
                                            b2, Wout, bout, out);
}

// Round 5
// 8292.561 us; speedup vs baseline: 1.0051x; 1.0051x over previous
//
#include <hip/hip_runtime.h>

#define BB 64
#define TT 4995
#define VV 4096
#define EE 100
#define UU 64
#define U3 192

// embW[v][k] = (emb @ W1 + b1[0])[v][k], 3.07 MB, L2-resident.
__device__ float g_embW[VV * U3];

__device__ __forceinline__ float fast_sigmoid(float x) {
    return __builtin_amdgcn_rcpf(1.0f + __expf(-x));
}
__device__ __forceinline__ float fast_tanh(float x) {
    return __builtin_amdgcn_rcpf(1.0f + __expf(-2.0f * x)) * 2.0f - 1.0f;
}
// Broadcast lane `lane` of v to all lanes (v_readlane -> SGPR, feeds FMA).
__device__ __forceinline__ float lane_bcast(float v, int lane) {
    return __int_as_float(__builtin_amdgcn_readlane(__float_as_int(v), lane));
}

// 64-way textual repetition: guarantees full unrolling + named scalars
// (no allocas, no dynamic indexing -> nothing the compiler can demote to
// scratch). Rounds 2-4 all had scratch-backed weight arrays (VGPR=108!).
#define REP64(M) \
  M(0) M(1) M(2) M(3) M(4) M(5) M(6) M(7) \
  M(8) M(9) M(10) M(11) M(12) M(13) M(14) M(15) \
  M(16) M(17) M(18) M(19) M(20) M(21) M(22) M(23) \
  M(24) M(25) M(26) M(27) M(28) M(29) M(30) M(31) \
  M(32) M(33) M(34) M(35) M(36) M(37) M(38) M(39) \
  M(40) M(41) M(42) M(43) M(44) M(45) M(46) M(47) \
  M(48) M(49) M(50) M(51) M(52) M(53) M(54) M(55) \
  M(56) M(57) M(58) M(59) M(60) M(61) M(62) M(63)

__global__ void gru_embw_kernel(const float* __restrict__ emb,
                                const float* __restrict__ W1,
                                const float* __restrict__ b1) {
    __shared__ float row[EE];
    const int v = blockIdx.x;
    const int k = threadIdx.x;  // 0..191
    if (k < EE) row[k] = emb[v * EE + k];
    __syncthreads();
    float acc = b1[k];
    #pragma unroll 4
    for (int j = 0; j < EE; ++j)
        acc = fmaf(row[j], W1[j * U3 + k], acc);
    g_embW[v * U3 + k] = acc;
}

// Fused 2-layer GRU scan. One workgroup (192 thr = 3 waves) per batch element.
// wave 0 -> z, wave 1 -> r, wave 2 -> candidate pieces. h1/h2 replicated per
// wave in registers; dots broadcast h via v_readlane on each wave's own SIMD
// (LDS broadcast would cost ~147 KB/step = LDS-BW-bound, round-2 lesson).
// Weights are 192 NAMED scalars pinned once -> must stay in VGPRs (~215 used).
__global__ __launch_bounds__(192, 1)
void gru_scan_kernel(const int* __restrict__ tokens,
                     const float* __restrict__ U1,
                     const float* __restrict__ b1,
                     const float* __restrict__ W2,
                     const float* __restrict__ U2,
                     const float* __restrict__ b2,
                     const float* __restrict__ Wout,
                     const float* __restrict__ bout,
                     float* __restrict__ out) {
    const int b = blockIdx.x;
    const int k = threadIdx.x;       // global col 0..191
    const int lane = k & 63;
    const int wave = k >> 6;         // 0=z, 1=r, 2=hh

    __shared__ float g1z[UU], g1r[UU], g1xh[UU], g1hph[UU];
    __shared__ float g2z[UU], g2r[UU], g2xh[UU], g2hph[UU];

    // ---- 192 named weight scalars, loaded once, pinned in VGPRs ----
#define DECL_W(i) float u1_##i, w2_##i, u2_##i;
    REP64(DECL_W)
#undef DECL_W
#define LOAD_W(i) u1_##i = U1[(i) * U3 + k]; \
                  w2_##i = W2[(i) * U3 + k]; \
                  u2_##i = U2[(i) * U3 + k];
    REP64(LOAD_W)
#undef LOAD_W
#define PIN_W(i) asm volatile("" : "+v"(u1_##i), "+v"(w2_##i), "+v"(u2_##i));
    REP64(PIN_W)
#undef PIN_W

    const float bu1 = b1[U3 + k];   // recurrent bias, layer 1
    const float b20 = b2[k];        // input bias, layer 2
    const float b21 = b2[U3 + k];   // recurrent bias, layer 2

    float hv1 = 0.0f, hv2 = 0.0f;   // h1[lane], h2[lane], replicated per wave

    const int* tokb = tokens + b * TT;
    int tok1 = tokb[1];
    float xk = g_embW[tokb[0] * U3 + k];   // xp1 (input bias folded in)

    #pragma unroll 1
    for (int t = 0; t < TT; ++t) {
        // prefetch: token 2 ahead, embW row 1 ahead (hides L2 latency)
        const int tnn = (t + 2 < TT) ? (t + 2) : (TT - 1);
        const int tok_nn = tokb[tnn];
        const float xk_next = g_embW[tok1 * U3 + k];

        // ---- layer-1 dot: acc = bu1 + sum_j h1[j] * U1[j, k] ----
        float a0 = bu1, a1 = 0.0f;
#define FMA_L1(i) { const float hb = lane_bcast(hv1, (i)); \
                    if ((i) & 1) a1 = fmaf(hb, u1_##i, a1); \
                    else         a0 = fmaf(hb, u1_##i, a0); }
        REP64(FMA_L1)
#undef FMA_L1
        const float acc = a0 + a1;

        if (wave == 0)      g1z[lane] = fast_sigmoid(xk + acc);
        else if (wave == 1) g1r[lane] = fast_sigmoid(xk + acc);
        else              { g1xh[lane] = xk; g1hph[lane] = acc; }
        __syncthreads();                                   // barrier 1

        // ---- h1 update: all waves redundantly, in-register ----
        {
            const float z  = g1z[lane];
            const float r  = g1r[lane];
            const float hh = fast_tanh(g1xh[lane] + r * g1hph[lane]);
            hv1 = z * hv1 + (1.0f - z) * hh;
        }

        // ---- layer-2 dual dot: c1 = b20 + h1.W2[:,k], c2 = b21 + h2.U2[:,k]
        float c1 = b20, c2 = b21;
#define FMA_L2(i) { c1 = fmaf(lane_bcast(hv1, (i)), w2_##i, c1); \
                    c2 = fmaf(lane_bcast(hv2, (i)), u2_##i, c2); }
        REP64(FMA_L2)
#undef FMA_L2

        if (wave == 0)      g2z[lane] = fast_sigmoid(c1 + c2);
        else if (wave == 1) g2r[lane] = fast_sigmoid(c1 + c2);
        else              { g2xh[lane] = c1; g2hph[lane] = c2; }
        __syncthreads();                                   // barrier 2

        // ---- h2 update: all waves redundantly, in-register ----
        {
            const float z  = g2z[lane];
            const float r  = g2r[lane];
            const float hh = fast_tanh(g2xh[lane] + r * g2hph[lane]);
            hv2 = z * hv2 + (1.0f - z) * hh;
        }

        xk = xk_next;
        tok1 = tok_nn;
    }

    // ---- output head: out[b] = sigmoid(h2 . Wout + bout) ----
    if (wave == 0) {
        float s = bout[0];
#define FMA_OUT(i) s = fmaf(lane_bcast(hv2, (i)), Wout[(i)], s);
        REP64(FMA_OUT)
#undef FMA_OUT
        if (lane == 0) out[b] = fast_sigmoid(s);
    }
}

extern "C" void kernel_launch(void* const* d_in, const int* in_sizes, int n_in,
                              void* d_out, int out_size, void* d_ws, size_t ws_size,
                              hipStream_t stream) {
    const int*   tokens = (const int*)  d_in[0];
    const float* emb    = (const float*)d_in[1];
    const float* W1     = (const float*)d_in[2];
    const float* U1w    = (const float*)d_in[3];
    const float* b1     = (const float*)d_in[4];
    const float* W2     = (const float*)d_in[5];
    const float* U2w    = (const float*)d_in[6];
    const float* b2     = (const float*)d_in[7];
    const float* Wout   = (const float*)d_in[8];
    const float* bout   = (const float*)d_in[9];
    float* out = (float*)d_out;

    gru_embw_kernel<<<VV, 192, 0, stream>>>(emb, W1, b1);
    gru_scan_kernel<<<BB, 192, 0, stream>>>(tokens, U1w, b1, W2, U2w,
                                            b2, Wout, bout, out);
}